// Round 14
// baseline (704.670 us; speedup 1.0000x reference)
//
#include <hip/hip_runtime.h>

// EGNN E_GCL fused kernels for MI355X (gfx950), bf16 MFMA path.
// Round 14: isolate the occupancy lever correctly. Re-audit of R9/R10
// failures: BOTH had a1hist at (256,3) (reg demand ~170 = right at the
// 3-wave/SIMD cliff -> corrupt A1 poisons everything); edge@(256,4) was
// never isolated (84 VGPR vs 128 cap - comfortable). This round = R13
// verbatim with ONLY edge launch_bounds 3->4 (LDS 35.3KB*4=141<=160,
// VGPR 84<=128). a1hist/nodecoord stay (256,2).
// R13 verified baseline: 637us total; edge ~399 (VALU 62%, occ 29%).

typedef float f32x4 __attribute__((ext_vector_type(4)));
typedef short s16x8 __attribute__((ext_vector_type(8)));

#define NN   50000
#define EE   1600000
#define NHF  6400000   // N*128
#define NBIN 50000
#define NT   25000     // 64-edge tiles
#define A1B  782       // a1 blocks in merged launch
#define NODB 782       // node blocks in merged launch

__device__ __forceinline__ unsigned short f2bf(float x){
  union { float f; unsigned int u; } v; v.f = x;
  unsigned int r = v.u + 0x7fffu + ((v.u >> 16) & 1u);
  return (unsigned short)(r >> 16);
}
__device__ __forceinline__ unsigned int pack2(float a, float b){
  unsigned int r;
  asm("v_cvt_pk_bf16_f32 %0, %1, %2" : "=v"(r) : "v"(a), "v"(b));
  return r;
}
__device__ __forceinline__ float silu_f(float x){
  return x * __builtin_amdgcn_rcpf(1.f + __expf(-x));
}
__device__ __forceinline__ float bflo(unsigned int u){ return __uint_as_float(u << 16); }
__device__ __forceinline__ float bfhi(unsigned int u){ return __uint_as_float(u & 0xffff0000u); }

__device__ __forceinline__ f32x4 mfma16(s16x8 a, s16x8 b, f32x4 c){
  return __builtin_amdgcn_mfma_f32_16x16x32_bf16(a, b, c, 0, 0, 0);
}

template<int CTRL> __device__ __forceinline__ float dppf(float x){
  return __int_as_float(__builtin_amdgcn_update_dpp(0, __float_as_int(x), CTRL, 0xF, 0xF, true));
}
template<int CTRL> __device__ __forceinline__ int dppi(int x){
  return __builtin_amdgcn_update_dpp(-1, x, CTRL, 0xF, 0xF, false);
}

__device__ __forceinline__ short* sptr(short* base, int fi, int slot){
  return (short*)((char*)base + (fi << 10) + (((slot << 4) ^ ((fi & 3) << 5))));
}

// ---------- weight pack: A-fragments of W^T ----------
// 0=We1a 1=We1b 2=We2 3=Wc1 4=Wn1a 5=Wn1b 6=Wn2
__global__ void pack_weights(const float* __restrict__ We1, const float* __restrict__ We2,
                             const float* __restrict__ Wc1, const float* __restrict__ Wn1,
                             const float* __restrict__ Wn2, short* __restrict__ wp)
{
  int b = blockIdx.x;              // 7*32 blocks, 64 threads
  int m = b >> 5, t = b & 31;
  int ft = t >> 2, ks = t & 3;
  int lane = threadIdx.x;
  const float* src;
  switch (m) {
    case 0: src = We1;            break;
    case 1: src = We1 + 128*128;  break;
    case 2: src = We2;            break;
    case 3: src = Wc1;            break;
    case 4: src = Wn1;            break;
    case 5: src = Wn1 + 128*128;  break;
    default: src = Wn2;           break;
  }
  short* dst = wp + m*16384 + (((ft<<2) + ks)*64 + lane)*8;
  int f  = (ft<<4) + (lane & 15);
  int kb = (ks<<5) + ((lane >> 4) << 3);
#pragma unroll
  for (int j = 0; j < 8; ++j)
    dst[j] = (short)f2bf(src[(kb + j)*128 + f]);
}

// ---------- merged: A1 pre-GEMM (blocks 0..781) || histogram (rest) ----------
// A1 layout per node (384 bf16): matrix mi in {0=We1a,1=We1b,2=Wn1a} at
// mi*128; within a matrix: (fti>>1)*32 + (lane>>4)*8 + (fti&1)*4 + j.
// Biases folded: mi==0 gets +be1, mi==2 gets +bn1.
__global__ __launch_bounds__(256, 2)
void a1hist_kernel(const float* __restrict__ h32, const short* __restrict__ wp,
                   const float* __restrict__ be1, const float* __restrict__ bn1,
                   unsigned short* __restrict__ A1,
                   const int* __restrict__ eidx, int* __restrict__ hist)
{
  if (blockIdx.x >= A1B) {            // histogram part
    int e = (blockIdx.x - A1B)*256 + threadIdx.x;
    if (e < EE) atomicAdd(&hist[eidx[e]], 1);
    return;
  }
  // A1 = h @ [We1a | We1b | Wn1a] (+ folded biases)
  __shared__ short sA[16][64][8];
  const int tid = threadIdx.x, w = tid >> 6, lane = tid & 63;
  const int n0 = blockIdx.x << 6;
  const int el = tid >> 2, q = tid & 3;
  const int fi0 = ((el >> 4) << 2) + q, er = el & 15;
  {
    const int node = n0 + el;
    if (node < NN) {
      const float* hp = h32 + (size_t)node*128 + q*32;
#pragma unroll
      for (int lg = 0; lg < 4; ++lg) {
        f32x4 u = *(const f32x4*)(hp + lg*8);
        f32x4 v = *(const f32x4*)(hp + lg*8 + 4);
        uint4 o;
        o.x = pack2(u.x, u.y); o.y = pack2(u.z, u.w);
        o.z = pack2(v.x, v.y); o.w = pack2(v.z, v.w);
        *(uint4*)&sA[fi0][lg*16 + er][0] = o;
      }
    } else {
      s16x8 z = {};
#pragma unroll
      for (int lg = 0; lg < 4; ++lg) *(s16x8*)&sA[fi0][lg*16 + er][0] = z;
    }
  }
  __syncthreads();

  static const int wpm[3] = {0, 1, 4};
#pragma unroll
  for (int p = 0; p < 2; ++p) {
    s16x8 af[3][4];
#pragma unroll
    for (int j = 0; j < 3; ++j) {
      const int ftg = w*6 + p*3 + j;
      const int mi = ftg >> 3, fti = ftg & 7;
#pragma unroll
      for (int ks = 0; ks < 4; ++ks)
        af[j][ks] = *(const s16x8*)(wp + wpm[mi]*16384 + (((fti<<2) + ks)*64 + lane)*8);
    }
    f32x4 acc[3][4] = {};
#pragma unroll
    for (int et = 0; et < 4; ++et)
#pragma unroll
      for (int ks = 0; ks < 4; ++ks) {
        s16x8 b = *(const s16x8*)&sA[et*4+ks][lane][0];
#pragma unroll
        for (int j = 0; j < 3; ++j)
          acc[j][et] = mfma16(af[j][ks], b, acc[j][et]);
      }
#pragma unroll
    for (int j = 0; j < 3; ++j) {
      const int ftg = w*6 + p*3 + j;
      const int mi = ftg >> 3, fti = ftg & 7;
      const int obase = mi*128 + ((fti >> 1) << 5) + ((fti & 1) << 2);
      const int ftrue = (fti << 4) + ((lane >> 4) << 2);
      f32x4 bia = {0.f, 0.f, 0.f, 0.f};
      if (mi == 0) bia = *(const f32x4*)(be1 + ftrue);
      else if (mi == 2) bia = *(const f32x4*)(bn1 + ftrue);
#pragma unroll
      for (int et = 0; et < 4; ++et) {
        const int node = n0 + et*16 + (lane & 15);
        if (node < NN) {
          f32x4 a = acc[j][et];
          uint2 o; o.x = pack2(a.x + bia.x, a.y + bia.y);
          o.y = pack2(a.z + bia.z, a.w + bia.w);
          *(uint2*)(A1 + (size_t)node*384 + obase + ((lane >> 4) << 3)) = o;
        }
      }
    }
  }
}

// ---------- 2-phase parallel scan; block offsets applied in scatter ----------
__global__ void scanA(const int* __restrict__ hist, int* __restrict__ cur,
                      int* __restrict__ btot)
{
  __shared__ int s[256];
  const int t = threadIdx.x;
  const int i = blockIdx.x*256 + t;
  int v = (i < NBIN) ? hist[i] : 0;
  s[t] = v; __syncthreads();
  int acc = v;
#pragma unroll
  for (int d = 1; d < 256; d <<= 1) {
    int u = (t >= d) ? s[t - d] : 0;
    __syncthreads();
    acc += u; s[t] = acc;
    __syncthreads();
  }
  if (i < NBIN) cur[i] = acc - v;             // block-local exclusive
  if (t == 255) btot[blockIdx.x] = acc;
}
__global__ void scanB(int* __restrict__ btot)
{
  __shared__ int s[256];
  const int t = threadIdx.x;
  int v = (t < 196) ? btot[t] : 0;
  s[t] = v; __syncthreads();
  int acc = v;
#pragma unroll
  for (int d = 1; d < 256; d <<= 1) {
    int u = (t >= d) ? s[t - d] : 0;
    __syncthreads();
    acc += u; s[t] = acc;
    __syncthreads();
  }
  if (t < 196) btot[t] = acc - v;             // exclusive block offsets
}

// scatter: sorted (row,col) pairs + per-edge coord-diff/radial precompute
__global__ void scatter_k(const int* __restrict__ eidx, int* __restrict__ cur,
                          const int* __restrict__ btot, const float* __restrict__ coord,
                          int2* __restrict__ rc, float* __restrict__ cdr)
{
  int e = blockIdx.x*256 + threadIdx.x;
  if (e < EE) {
    int r = eidx[e], c = eidx[EE + e];
    int p = atomicAdd(&cur[r], 1) + btot[r >> 8];
    int2 v; v.x = r; v.y = c;
    rc[p] = v;
    float dx = coord[3*r+0] - coord[3*c+0];
    float dy = coord[3*r+1] - coord[3*c+1];
    float dz = coord[3*r+2] - coord[3*c+2];
    f32x4 o; o.x = dx; o.y = dy; o.z = dz; o.w = dx*dx + dy*dy + dz*dz;
    *(f32x4*)(cdr + 4*(size_t)p) = o;
  }
}

// ---------- edge kernel (register metadata; 3 barriers/tile; 4 blocks/CU) ---
__global__ __launch_bounds__(256, 4)
void edge_kernel(const unsigned short* __restrict__ A1, const float* __restrict__ cdr,
                 const int2* __restrict__ rc, const short* __restrict__ wp,
                 const float* __restrict__ be2, const float* __restrict__ bc1,
                 const float* __restrict__ We1, const float* __restrict__ Wc2,
                 float* __restrict__ aggh, float* __restrict__ aggc,
                 float* __restrict__ cntb)
{
  __shared__ short sAf[2][16*64*8];      // 32 KiB swizzled frag tiles: t1 / ef
  __shared__ float s_vec[4][128];        // be2, bc1, W1c, Wc2
  __shared__ float s_phi[64];

  const int tid  = threadIdx.x;
  const int w    = tid >> 6, lane = tid & 63;
  const int ecol = lane & 15, rgrp = lane >> 4;

  if (tid < 128) {
    s_vec[0][tid] = be2[tid];
    s_vec[1][tid] = bc1[tid];
    s_vec[2][tid] = We1[256*128 + tid];   // W1c (radial row of We1)
    s_vec[3][tid] = Wc2[tid];
  }

  // persistent weights: We2 + Wc1 = 64 VGPR
  s16x8 wf2[2][4], wf3[2][4];
#pragma unroll
  for (int f2 = 0; f2 < 2; ++f2)
#pragma unroll
    for (int ks = 0; ks < 4; ++ks) {
      wf2[f2][ks] = *(const s16x8*)(wp + 2*16384 + ((((2*w+f2)<<2) + ks)*64 + lane)*8);
      wf3[f2][ks] = *(const s16x8*)(wp + 3*16384 + ((((2*w+f2)<<2) + ks)*64 + lane)*8);
    }
  __syncthreads();                       // P0 (once): s_vec visible to all

  short* sb0 = &sAf[0][0];
  short* sb1 = &sAf[1][0];

  const int tbeg = blockIdx.x * 13;
  const int tend = (tbeg + 13 < NT) ? tbeg + 13 : NT;
  const int gbase = (w << 5) + (rgrp << 3);   // gather base within a matrix slab

  for (int t = tbeg; t < tend; ++t) {
    const int e0 = t << 6;

    // per-thread edge metadata (L1-broadcast within wave; one block per tile)
    int rr[4], cc[4]; float rd[4];
#pragma unroll
    for (int et = 0; et < 4; ++et) {
      int2 v = rc[e0 + et*16 + ecol];
      rr[et] = v.x; cc[et] = v.y;
      rd[et] = cdr[4*(size_t)(e0 + et*16 + ecol) + 3];
    }
    if (tid < 64) s_phi[tid] = 0.f;      // pre-S1: ordered before post-S2 atomics

    // ep0: t1 = silu(A1r[row] + A1c[col] + rad*W1c) -> frags into sb0
    {
      uint4 gr4[4], gc4[4];
#pragma unroll
      for (int et = 0; et < 4; ++et) {
        gr4[et] = *(const uint4*)(A1 + (size_t)rr[et]*384 + gbase);
        gc4[et] = *(const uint4*)(A1 + (size_t)cc[et]*384 + 128 + gbase);
      }
#pragma unroll
      for (int f2 = 0; f2 < 2; ++f2) {
        const int f0 = (2*w+f2)*16 + (rgrp << 2);
        const int ks2 = f0 >> 5, lg2 = (f0 & 31) >> 3, j0 = f0 & 7;
        f32x4 w1c = *(const f32x4*)&s_vec[2][f0];
#pragma unroll
        for (int et = 0; et < 4; ++et) {
          uint2 rv, cv;
          rv.x = f2 ? gr4[et].z : gr4[et].x;
          rv.y = f2 ? gr4[et].w : gr4[et].y;
          cv.x = f2 ? gc4[et].z : gc4[et].x;
          cv.y = f2 ? gc4[et].w : gc4[et].y;
          f32x4 x;
          x.x = silu_f(bflo(rv.x) + bflo(cv.x) + rd[et]*w1c.x);
          x.y = silu_f(bfhi(rv.x) + bfhi(cv.x) + rd[et]*w1c.y);
          x.z = silu_f(bflo(rv.y) + bflo(cv.y) + rd[et]*w1c.z);
          x.w = silu_f(bfhi(rv.y) + bfhi(cv.y) + rd[et]*w1c.w);
          uint2 p; p.x = pack2(x.x, x.y); p.y = pack2(x.z, x.w);
          *(uint2*)((char*)sptr(sb0, et*4 + ks2, lg2*16 + ecol) + 2*j0) = p;
        }
      }
    }
    __syncthreads();                                            // S1

    // GEMM2: ef = silu(t1 @ We2 + be2)
    f32x4 a2[2][4] = {};
#pragma unroll
    for (int et = 0; et < 4; ++et)
#pragma unroll
      for (int ks = 0; ks < 4; ++ks) {
        s16x8 b = *(const s16x8*)sptr(sb0, et*4+ks, lane);
        a2[0][et] = mfma16(wf2[0][ks], b, a2[0][et]);
        a2[1][et] = mfma16(wf2[1][ks], b, a2[1][et]);
      }
    // ep2: SiLU; frags into sb1; DPP segmented suffix-sum dedup -> agg_h atomics
#pragma unroll
    for (int et = 0; et < 4; ++et) {
      const int r_l = rr[et];
      f32x4 xx0, xx1;
#pragma unroll
      for (int f2 = 0; f2 < 2; ++f2) {
        const int f0 = (2*w+f2)*16 + (rgrp << 2);
        const int ks2 = f0 >> 5, lg2 = (f0 & 31) >> 3, j0 = f0 & 7;
        f32x4 b2 = *(const f32x4*)&s_vec[0][f0];
        f32x4 x = a2[f2][et];
        x.x = silu_f(x.x + b2.x); x.y = silu_f(x.y + b2.y);
        x.z = silu_f(x.z + b2.z); x.w = silu_f(x.w + b2.w);
        uint2 p; p.x = pack2(x.x, x.y); p.y = pack2(x.z, x.w);
        *(uint2*)((char*)sptr(sb1, et*4 + ks2, lg2*16 + ecol) + 2*j0) = p;
        if (f2 == 0) xx0 = x; else xx1 = x;
      }
#define SEG_ROUND(CTRL) { \
      int rn = dppi<CTRL>(r_l); \
      float m = (rn == r_l) ? 1.f : 0.f; \
      xx0.x += dppf<CTRL>(xx0.x)*m; \
      xx0.y += dppf<CTRL>(xx0.y)*m; \
      xx0.z += dppf<CTRL>(xx0.z)*m; \
      xx0.w += dppf<CTRL>(xx0.w)*m; \
      xx1.x += dppf<CTRL>(xx1.x)*m; \
      xx1.y += dppf<CTRL>(xx1.y)*m; \
      xx1.z += dppf<CTRL>(xx1.z)*m; \
      xx1.w += dppf<CTRL>(xx1.w)*m; }
      SEG_ROUND(0x101)
      SEG_ROUND(0x102)
      SEG_ROUND(0x104)
      SEG_ROUND(0x108)
#undef SEG_ROUND
      const int rprev = dppi<0x111>(r_l);
      if (rprev != r_l) {
        const int f0a = (2*w+0)*16 + (rgrp << 2);
        const int f0b = (2*w+1)*16 + (rgrp << 2);
        float* aga = aggh + (size_t)r_l*128 + f0a;
        float* agb = aggh + (size_t)r_l*128 + f0b;
        atomicAdd(aga+0, xx0.x); atomicAdd(aga+1, xx0.y);
        atomicAdd(aga+2, xx0.z); atomicAdd(aga+3, xx0.w);
        atomicAdd(agb+0, xx1.x); atomicAdd(agb+1, xx1.y);
        atomicAdd(agb+2, xx1.z); atomicAdd(agb+3, xx1.w);
      }
    }
    __syncthreads();                                            // S2

    // GEMM3: phi = silu(ef@Wc1+bc1) @ Wc2
    f32x4 a3[2][4] = {};
#pragma unroll
    for (int et = 0; et < 4; ++et)
#pragma unroll
      for (int ks = 0; ks < 4; ++ks) {
        s16x8 b = *(const s16x8*)sptr(sb1, et*4+ks, lane);
        a3[0][et] = mfma16(wf3[0][ks], b, a3[0][et]);
        a3[1][et] = mfma16(wf3[1][ks], b, a3[1][et]);
      }
#pragma unroll
    for (int et = 0; et < 4; ++et) {
      float p = 0.f;
#pragma unroll
      for (int f2 = 0; f2 < 2; ++f2) {
        const int f0 = (2*w+f2)*16 + (rgrp << 2);
        f32x4 bc = *(const f32x4*)&s_vec[1][f0];
        f32x4 wc = *(const f32x4*)&s_vec[3][f0];
        f32x4 x = a3[f2][et];
        p += silu_f(x.x + bc.x)*wc.x + silu_f(x.y + bc.y)*wc.y
           + silu_f(x.z + bc.z)*wc.z + silu_f(x.w + bc.w)*wc.w;
      }
      p += __shfl_xor(p, 16);
      p += __shfl_xor(p, 32);
      if (rgrp == 0) atomicAdd(&s_phi[et*16 + ecol], p);
    }
    __syncthreads();                                            // S3

    // coord aggregation (wave0): reload own lanes coalesced; segmented scan
    if (tid < 64) {
      int2 v = rc[e0 + tid];
      int r = v.x;
      f32x4 cd = *(const f32x4*)(cdr + 4*(size_t)(e0 + tid));
      float ph = s_phi[tid];
      float cx = cd.x*ph, cy = cd.y*ph, cz = cd.z*ph, c1 = 1.f;
#pragma unroll
      for (int d = 1; d < 64; d <<= 1) {
        const int sl = tid + d;
        int   r2 = __shfl(r,  sl, 64);
        float ux = __shfl(cx, sl, 64), uy = __shfl(cy, sl, 64);
        float uz = __shfl(cz, sl, 64), uw = __shfl(c1, sl, 64);
        if ((sl < 64) && (r2 == r)) { cx+=ux; cy+=uy; cz+=uz; c1+=uw; }
      }
      const int rp = __shfl(r, tid - 1, 64);
      if (tid == 0 || rp != r) {
        atomicAdd(&aggc[3*r+0], cx); atomicAdd(&aggc[3*r+1], cy);
        atomicAdd(&aggc[3*r+2], cz); atomicAdd(&cntb[r], c1);
      }
    }
    // no S4: sb0's next write is post-S3 for every wave; s_phi zero-write is
    // pre-S1(t+1) < post-S2(t+1) atomics; wave0 is sole s_phi[tid] reader.
  }
}

// ---------- merged: node model (blocks 0..781) || coord update (rest) -------
__global__ __launch_bounds__(256, 2)
void nodecoord_kernel(const unsigned short* __restrict__ A1, const float* __restrict__ h32,
                      const short* __restrict__ wp, const float* __restrict__ bn2,
                      const float* __restrict__ coord, const float* __restrict__ aggc,
                      const float* __restrict__ cntb, float* __restrict__ hout)
{
  if (blockIdx.x >= NODB) {           // coord part
    int i = (blockIdx.x - NODB)*256 + threadIdx.x;
    if (i < NN) {
      float inv = __builtin_amdgcn_rcpf(fmaxf(cntb[i], 1.f));
      hout[NHF + 3*i+0] = coord[3*i+0] + aggc[3*i+0]*inv;
      hout[NHF + 3*i+1] = coord[3*i+1] + aggc[3*i+1]*inv;
      hout[NHF + 3*i+2] = coord[3*i+2] + aggc[3*i+2]*inv;
    }
    return;
  }
  // node: h_out = h + silu(A1n + agg_h@Wn1b) @ Wn2 + bn2   (bn1 folded in A1)
  __shared__ short sA[16][64][8];
  __shared__ float s_vec[128];
  const int tid  = threadIdx.x, w = tid >> 6, lane = tid & 63;
  const int ecol = lane & 15, rgrp = lane >> 4;
  if (tid < 128) s_vec[tid] = bn2[tid];

  s16x8 wfa[2][4], wfb[2][4];          // Wn1b, Wn2
#pragma unroll
  for (int f2 = 0; f2 < 2; ++f2)
#pragma unroll
    for (int ks = 0; ks < 4; ++ks) {
      wfa[f2][ks] = *(const s16x8*)(wp + 5*16384 + ((((2*w+f2)<<2) + ks)*64 + lane)*8);
      wfb[f2][ks] = *(const s16x8*)(wp + 6*16384 + ((((2*w+f2)<<2) + ks)*64 + lane)*8);
    }

  const int n0 = blockIdx.x << 6;
  const int el = tid >> 2, q = tid & 3;
  const int fi0 = ((el >> 4) << 2) + q, er = el & 15;
  { // stage agg_h (lives in d_out h region) as bf16 frags
    const int node = n0 + el;
    if (node < NN) {
      const float* ap = hout + (size_t)node*128 + q*32;
#pragma unroll
      for (int lg = 0; lg < 4; ++lg) {
        f32x4 u = *(const f32x4*)(ap + lg*8);
        f32x4 v = *(const f32x4*)(ap + lg*8 + 4);
        uint4 o;
        o.x = pack2(u.x, u.y); o.y = pack2(u.z, u.w);
        o.z = pack2(v.x, v.y); o.w = pack2(v.z, v.w);
        *(uint4*)&sA[fi0][lg*16 + er][0] = o;
      }
    } else {
      s16x8 z = {};
#pragma unroll
      for (int lg = 0; lg < 4; ++lg) *(s16x8*)&sA[fi0][lg*16 + er][0] = z;
    }
  }
  __syncthreads();

  f32x4 acc[2][4] = {};
#pragma unroll
  for (int et = 0; et < 4; ++et)
#pragma unroll
    for (int ks = 0; ks < 4; ++ks) {
      s16x8 ba = *(const s16x8*)&sA[et*4+ks][lane][0];
      acc[0][et] = mfma16(wfa[0][ks], ba, acc[0][et]);
      acc[1][et] = mfma16(wfa[1][ks], ba, acc[1][et]);
    }
  __syncthreads();   // all reads of sA done; safe to overwrite with t frags

  // A1n gathers (gather-friendly layout: one uint4 per et covers both f2)
  uint4 g4[4];
  {
    const int gb = 256 + (w << 5) + (rgrp << 3);
#pragma unroll
    for (int et = 0; et < 4; ++et) {
      const int node = n0 + et*16 + ecol;
      if (node < NN) g4[et] = *(const uint4*)(A1 + (size_t)node*384 + gb);
      else { g4[et].x = 0u; g4[et].y = 0u; g4[et].z = 0u; g4[et].w = 0u; }
    }
  }
  // ep: t = silu(acc + A1n[node]) -> frags back into sA
#pragma unroll
  for (int f2 = 0; f2 < 2; ++f2) {
    const int ft = 2*w + f2, f0 = ft*16 + (rgrp << 2);
    const int ks2 = f0 >> 5, lg2 = (f0 & 31) >> 3, j0 = f0 & 7;
#pragma unroll
    for (int et = 0; et < 4; ++et) {
      uint2 g;
      g.x = f2 ? g4[et].z : g4[et].x;
      g.y = f2 ? g4[et].w : g4[et].y;
      f32x4 x = acc[f2][et];
      x.x = silu_f(x.x + bflo(g.x));
      x.y = silu_f(x.y + bfhi(g.x));
      x.z = silu_f(x.z + bflo(g.y));
      x.w = silu_f(x.w + bfhi(g.y));
      uint2 p; p.x = pack2(x.x, x.y); p.y = pack2(x.z, x.w);
      *(uint2*)&sA[et*4 + ks2][lg2*16 + ecol][j0] = p;
    }
  }
  __syncthreads();

  f32x4 a2[2][4] = {};
#pragma unroll
  for (int et = 0; et < 4; ++et)
#pragma unroll
    for (int ks = 0; ks < 4; ++ks) {
      s16x8 b = *(const s16x8*)&sA[et*4+ks][lane][0];
      a2[0][et] = mfma16(wfb[0][ks], b, a2[0][et]);
      a2[1][et] = mfma16(wfb[1][ks], b, a2[1][et]);
    }
  // h_out = h + a2 + bn2, written directly (16B per lane)
#pragma unroll
  for (int f2 = 0; f2 < 2; ++f2) {
    const int f0 = (2*w+f2)*16 + (rgrp << 2);
    f32x4 b2 = *(const f32x4*)&s_vec[f0];
#pragma unroll
    for (int et = 0; et < 4; ++et) {
      const int node = n0 + et*16 + ecol;
      if (node < NN) {
        f32x4 hv = *(const f32x4*)(h32 + (size_t)node*128 + f0);
        f32x4 x = a2[f2][et];
        x.x += b2.x + hv.x; x.y += b2.y + hv.y;
        x.z += b2.z + hv.z; x.w += b2.w + hv.w;
        *(f32x4*)(hout + (size_t)node*128 + f0) = x;
      }
    }
  }
}

extern "C" void kernel_launch(void* const* d_in, const int* in_sizes, int n_in,
                              void* d_out, int out_size, void* d_ws, size_t ws_size,
                              hipStream_t stream)
{
  (void)in_sizes; (void)n_in; (void)out_size; (void)ws_size;
  const float* h    = (const float*)d_in[0];
  const float* crd  = (const float*)d_in[1];
  const int*   eidx = (const int*)  d_in[2];
  const float* We1  = (const float*)d_in[3];
  const float* be1  = (const float*)d_in[4];
  const float* We2  = (const float*)d_in[5];
  const float* be2  = (const float*)d_in[6];
  const float* Wn1  = (const float*)d_in[7];
  const float* bn1  = (const float*)d_in[8];
  const float* Wn2  = (const float*)d_in[9];
  const float* bn2  = (const float*)d_in[10];
  const float* Wc1  = (const float*)d_in[11];
  const float* bc1  = (const float*)d_in[12];
  const float* Wc2  = (const float*)d_in[13];
  float* out = (float*)d_out;
  char*  ws  = (char*)d_ws;

  short*          wp   = (short*)ws;                       //    229,376 B
  unsigned short* A1   = (unsigned short*)(ws + 229376);   // 38,400,000 B
  float*          aggc = (float*)(ws + 38629376);          //    600,000 B
  float*          cntb = (float*)(ws + 39229376);          //    200,000 B
  int*            hist = (int*)  (ws + 39429376);          //    200,000 B
  int*            cur  = (int*)  (ws + 39629376);          //    200,000 B
  int*            btot = (int*)  (ws + 39829376);          //      1,024 B
  int2*           rc   = (int2*) (ws + 39830400);          // 12,800,000 B
  float*          cdr  = (float*)(ws + 52630400);          // 25,600,000 B (end 78,230,400)

  // zero accumulators every call (harness does not re-poison between replays)
  hipMemsetAsync(out, 0, (size_t)NHF*4, stream);           // agg_h region of d_out
  hipMemsetAsync(ws + 38629376, 0, 800000, stream);        // agg_c + cnt
  hipMemsetAsync(ws + 39429376, 0, 200000, stream);        // hist

  pack_weights<<<dim3(224), dim3(64), 0, stream>>>(We1, We2, Wc1, Wn1, Wn2, wp);
  a1hist_kernel<<<dim3(A1B + 6250), dim3(256), 0, stream>>>(h, wp, be1, bn1, A1, eidx, hist);
  scanA<<<dim3(196), dim3(256), 0, stream>>>(hist, cur, btot);
  scanB<<<dim3(1), dim3(256), 0, stream>>>(btot);
  scatter_k<<<dim3(6250), dim3(256), 0, stream>>>(eidx, cur, btot, crd, rc, cdr);
  edge_kernel<<<dim3(1924), dim3(256), 0, stream>>>(A1, cdr, rc, wp,
                                                    be2, bc1, We1, Wc2,
                                                    out, aggc, cntb);
  nodecoord_kernel<<<dim3(NODB + 196), dim3(256), 0, stream>>>(A1, h, wp, bn2,
                                                               crd, aggc, cntb, out);
}

// Round 15
// 614.733 us; speedup vs baseline: 1.1463x; 1.1463x over previous
//
#include <hip/hip_runtime.h>

// EGNN E_GCL fused kernels for MI355X (gfx950), bf16 MFMA path.
// Round 15: revert R14's edge@(256,4) experiment (passed correctness but
// compiler capped VGPR at 64 -> persistent weight frags demoted to memory
// reloads: FETCH 174->360MB, edge 396->478us). This restores R13 verbatim -
// the best verified configuration (637us). Occupancy lever now closed in
// both directions: (256,3)=84 VGPR comfortable / (256,4)=weight spill.
// Ledger: atomic-dedup, silu-rcp+cvt_pk, A1 hoist, rc/cdr precompute, uint4
// gather layout = banked wins. Pipelining x2, occupancy x2, barrier cuts =
// exhausted. Edge: VALU 62% (~245us irreducible per-edge math) + latency.

typedef float f32x4 __attribute__((ext_vector_type(4)));
typedef short s16x8 __attribute__((ext_vector_type(8)));

#define NN   50000
#define EE   1600000
#define NHF  6400000   // N*128
#define NBIN 50000
#define NT   25000     // 64-edge tiles
#define A1B  782       // a1 blocks in merged launch
#define NODB 782       // node blocks in merged launch

__device__ __forceinline__ unsigned short f2bf(float x){
  union { float f; unsigned int u; } v; v.f = x;
  unsigned int r = v.u + 0x7fffu + ((v.u >> 16) & 1u);
  return (unsigned short)(r >> 16);
}
__device__ __forceinline__ unsigned int pack2(float a, float b){
  unsigned int r;
  asm("v_cvt_pk_bf16_f32 %0, %1, %2" : "=v"(r) : "v"(a), "v"(b));
  return r;
}
__device__ __forceinline__ float silu_f(float x){
  return x * __builtin_amdgcn_rcpf(1.f + __expf(-x));
}
__device__ __forceinline__ float bflo(unsigned int u){ return __uint_as_float(u << 16); }
__device__ __forceinline__ float bfhi(unsigned int u){ return __uint_as_float(u & 0xffff0000u); }

__device__ __forceinline__ f32x4 mfma16(s16x8 a, s16x8 b, f32x4 c){
  return __builtin_amdgcn_mfma_f32_16x16x32_bf16(a, b, c, 0, 0, 0);
}

template<int CTRL> __device__ __forceinline__ float dppf(float x){
  return __int_as_float(__builtin_amdgcn_update_dpp(0, __float_as_int(x), CTRL, 0xF, 0xF, true));
}
template<int CTRL> __device__ __forceinline__ int dppi(int x){
  return __builtin_amdgcn_update_dpp(-1, x, CTRL, 0xF, 0xF, false);
}

__device__ __forceinline__ short* sptr(short* base, int fi, int slot){
  return (short*)((char*)base + (fi << 10) + (((slot << 4) ^ ((fi & 3) << 5))));
}

// ---------- weight pack: A-fragments of W^T ----------
// 0=We1a 1=We1b 2=We2 3=Wc1 4=Wn1a 5=Wn1b 6=Wn2
__global__ void pack_weights(const float* __restrict__ We1, const float* __restrict__ We2,
                             const float* __restrict__ Wc1, const float* __restrict__ Wn1,
                             const float* __restrict__ Wn2, short* __restrict__ wp)
{
  int b = blockIdx.x;              // 7*32 blocks, 64 threads
  int m = b >> 5, t = b & 31;
  int ft = t >> 2, ks = t & 3;
  int lane = threadIdx.x;
  const float* src;
  switch (m) {
    case 0: src = We1;            break;
    case 1: src = We1 + 128*128;  break;
    case 2: src = We2;            break;
    case 3: src = Wc1;            break;
    case 4: src = Wn1;            break;
    case 5: src = Wn1 + 128*128;  break;
    default: src = Wn2;           break;
  }
  short* dst = wp + m*16384 + (((ft<<2) + ks)*64 + lane)*8;
  int f  = (ft<<4) + (lane & 15);
  int kb = (ks<<5) + ((lane >> 4) << 3);
#pragma unroll
  for (int j = 0; j < 8; ++j)
    dst[j] = (short)f2bf(src[(kb + j)*128 + f]);
}

// ---------- merged: A1 pre-GEMM (blocks 0..781) || histogram (rest) ----------
// A1 layout per node (384 bf16): matrix mi in {0=We1a,1=We1b,2=Wn1a} at
// mi*128; within a matrix: (fti>>1)*32 + (lane>>4)*8 + (fti&1)*4 + j.
// Biases folded: mi==0 gets +be1, mi==2 gets +bn1.
__global__ __launch_bounds__(256, 2)
void a1hist_kernel(const float* __restrict__ h32, const short* __restrict__ wp,
                   const float* __restrict__ be1, const float* __restrict__ bn1,
                   unsigned short* __restrict__ A1,
                   const int* __restrict__ eidx, int* __restrict__ hist)
{
  if (blockIdx.x >= A1B) {            // histogram part
    int e = (blockIdx.x - A1B)*256 + threadIdx.x;
    if (e < EE) atomicAdd(&hist[eidx[e]], 1);
    return;
  }
  // A1 = h @ [We1a | We1b | Wn1a] (+ folded biases)
  __shared__ short sA[16][64][8];
  const int tid = threadIdx.x, w = tid >> 6, lane = tid & 63;
  const int n0 = blockIdx.x << 6;
  const int el = tid >> 2, q = tid & 3;
  const int fi0 = ((el >> 4) << 2) + q, er = el & 15;
  {
    const int node = n0 + el;
    if (node < NN) {
      const float* hp = h32 + (size_t)node*128 + q*32;
#pragma unroll
      for (int lg = 0; lg < 4; ++lg) {
        f32x4 u = *(const f32x4*)(hp + lg*8);
        f32x4 v = *(const f32x4*)(hp + lg*8 + 4);
        uint4 o;
        o.x = pack2(u.x, u.y); o.y = pack2(u.z, u.w);
        o.z = pack2(v.x, v.y); o.w = pack2(v.z, v.w);
        *(uint4*)&sA[fi0][lg*16 + er][0] = o;
      }
    } else {
      s16x8 z = {};
#pragma unroll
      for (int lg = 0; lg < 4; ++lg) *(s16x8*)&sA[fi0][lg*16 + er][0] = z;
    }
  }
  __syncthreads();

  static const int wpm[3] = {0, 1, 4};
#pragma unroll
  for (int p = 0; p < 2; ++p) {
    s16x8 af[3][4];
#pragma unroll
    for (int j = 0; j < 3; ++j) {
      const int ftg = w*6 + p*3 + j;
      const int mi = ftg >> 3, fti = ftg & 7;
#pragma unroll
      for (int ks = 0; ks < 4; ++ks)
        af[j][ks] = *(const s16x8*)(wp + wpm[mi]*16384 + (((fti<<2) + ks)*64 + lane)*8);
    }
    f32x4 acc[3][4] = {};
#pragma unroll
    for (int et = 0; et < 4; ++et)
#pragma unroll
      for (int ks = 0; ks < 4; ++ks) {
        s16x8 b = *(const s16x8*)&sA[et*4+ks][lane][0];
#pragma unroll
        for (int j = 0; j < 3; ++j)
          acc[j][et] = mfma16(af[j][ks], b, acc[j][et]);
      }
#pragma unroll
    for (int j = 0; j < 3; ++j) {
      const int ftg = w*6 + p*3 + j;
      const int mi = ftg >> 3, fti = ftg & 7;
      const int obase = mi*128 + ((fti >> 1) << 5) + ((fti & 1) << 2);
      const int ftrue = (fti << 4) + ((lane >> 4) << 2);
      f32x4 bia = {0.f, 0.f, 0.f, 0.f};
      if (mi == 0) bia = *(const f32x4*)(be1 + ftrue);
      else if (mi == 2) bia = *(const f32x4*)(bn1 + ftrue);
#pragma unroll
      for (int et = 0; et < 4; ++et) {
        const int node = n0 + et*16 + (lane & 15);
        if (node < NN) {
          f32x4 a = acc[j][et];
          uint2 o; o.x = pack2(a.x + bia.x, a.y + bia.y);
          o.y = pack2(a.z + bia.z, a.w + bia.w);
          *(uint2*)(A1 + (size_t)node*384 + obase + ((lane >> 4) << 3)) = o;
        }
      }
    }
  }
}

// ---------- 2-phase parallel scan; block offsets applied in scatter ----------
__global__ void scanA(const int* __restrict__ hist, int* __restrict__ cur,
                      int* __restrict__ btot)
{
  __shared__ int s[256];
  const int t = threadIdx.x;
  const int i = blockIdx.x*256 + t;
  int v = (i < NBIN) ? hist[i] : 0;
  s[t] = v; __syncthreads();
  int acc = v;
#pragma unroll
  for (int d = 1; d < 256; d <<= 1) {
    int u = (t >= d) ? s[t - d] : 0;
    __syncthreads();
    acc += u; s[t] = acc;
    __syncthreads();
  }
  if (i < NBIN) cur[i] = acc - v;             // block-local exclusive
  if (t == 255) btot[blockIdx.x] = acc;
}
__global__ void scanB(int* __restrict__ btot)
{
  __shared__ int s[256];
  const int t = threadIdx.x;
  int v = (t < 196) ? btot[t] : 0;
  s[t] = v; __syncthreads();
  int acc = v;
#pragma unroll
  for (int d = 1; d < 256; d <<= 1) {
    int u = (t >= d) ? s[t - d] : 0;
    __syncthreads();
    acc += u; s[t] = acc;
    __syncthreads();
  }
  if (t < 196) btot[t] = acc - v;             // exclusive block offsets
}

// scatter: sorted (row,col) pairs + per-edge coord-diff/radial precompute
__global__ void scatter_k(const int* __restrict__ eidx, int* __restrict__ cur,
                          const int* __restrict__ btot, const float* __restrict__ coord,
                          int2* __restrict__ rc, float* __restrict__ cdr)
{
  int e = blockIdx.x*256 + threadIdx.x;
  if (e < EE) {
    int r = eidx[e], c = eidx[EE + e];
    int p = atomicAdd(&cur[r], 1) + btot[r >> 8];
    int2 v; v.x = r; v.y = c;
    rc[p] = v;
    float dx = coord[3*r+0] - coord[3*c+0];
    float dy = coord[3*r+1] - coord[3*c+1];
    float dz = coord[3*r+2] - coord[3*c+2];
    f32x4 o; o.x = dx; o.y = dy; o.z = dz; o.w = dx*dx + dy*dy + dz*dz;
    *(f32x4*)(cdr + 4*(size_t)p) = o;
  }
}

// ---------- edge kernel (register metadata; 3 barriers/tile) ----------
__global__ __launch_bounds__(256, 3)
void edge_kernel(const unsigned short* __restrict__ A1, const float* __restrict__ cdr,
                 const int2* __restrict__ rc, const short* __restrict__ wp,
                 const float* __restrict__ be2, const float* __restrict__ bc1,
                 const float* __restrict__ We1, const float* __restrict__ Wc2,
                 float* __restrict__ aggh, float* __restrict__ aggc,
                 float* __restrict__ cntb)
{
  __shared__ short sAf[2][16*64*8];      // 32 KiB swizzled frag tiles: t1 / ef
  __shared__ float s_vec[4][128];        // be2, bc1, W1c, Wc2
  __shared__ float s_phi[64];

  const int tid  = threadIdx.x;
  const int w    = tid >> 6, lane = tid & 63;
  const int ecol = lane & 15, rgrp = lane >> 4;

  if (tid < 128) {
    s_vec[0][tid] = be2[tid];
    s_vec[1][tid] = bc1[tid];
    s_vec[2][tid] = We1[256*128 + tid];   // W1c (radial row of We1)
    s_vec[3][tid] = Wc2[tid];
  }

  // persistent weights: We2 + Wc1 = 64 VGPR
  s16x8 wf2[2][4], wf3[2][4];
#pragma unroll
  for (int f2 = 0; f2 < 2; ++f2)
#pragma unroll
    for (int ks = 0; ks < 4; ++ks) {
      wf2[f2][ks] = *(const s16x8*)(wp + 2*16384 + ((((2*w+f2)<<2) + ks)*64 + lane)*8);
      wf3[f2][ks] = *(const s16x8*)(wp + 3*16384 + ((((2*w+f2)<<2) + ks)*64 + lane)*8);
    }
  __syncthreads();                       // P0 (once): s_vec visible to all

  short* sb0 = &sAf[0][0];
  short* sb1 = &sAf[1][0];

  const int tbeg = blockIdx.x * 13;
  const int tend = (tbeg + 13 < NT) ? tbeg + 13 : NT;
  const int gbase = (w << 5) + (rgrp << 3);   // gather base within a matrix slab

  for (int t = tbeg; t < tend; ++t) {
    const int e0 = t << 6;

    // per-thread edge metadata (L1-broadcast within wave; one block per tile)
    int rr[4], cc[4]; float rd[4];
#pragma unroll
    for (int et = 0; et < 4; ++et) {
      int2 v = rc[e0 + et*16 + ecol];
      rr[et] = v.x; cc[et] = v.y;
      rd[et] = cdr[4*(size_t)(e0 + et*16 + ecol) + 3];
    }
    if (tid < 64) s_phi[tid] = 0.f;      // pre-S1: ordered before post-S2 atomics

    // ep0: t1 = silu(A1r[row] + A1c[col] + rad*W1c) -> frags into sb0
    {
      uint4 gr4[4], gc4[4];
#pragma unroll
      for (int et = 0; et < 4; ++et) {
        gr4[et] = *(const uint4*)(A1 + (size_t)rr[et]*384 + gbase);
        gc4[et] = *(const uint4*)(A1 + (size_t)cc[et]*384 + 128 + gbase);
      }
#pragma unroll
      for (int f2 = 0; f2 < 2; ++f2) {
        const int f0 = (2*w+f2)*16 + (rgrp << 2);
        const int ks2 = f0 >> 5, lg2 = (f0 & 31) >> 3, j0 = f0 & 7;
        f32x4 w1c = *(const f32x4*)&s_vec[2][f0];
#pragma unroll
        for (int et = 0; et < 4; ++et) {
          uint2 rv, cv;
          rv.x = f2 ? gr4[et].z : gr4[et].x;
          rv.y = f2 ? gr4[et].w : gr4[et].y;
          cv.x = f2 ? gc4[et].z : gc4[et].x;
          cv.y = f2 ? gc4[et].w : gc4[et].y;
          f32x4 x;
          x.x = silu_f(bflo(rv.x) + bflo(cv.x) + rd[et]*w1c.x);
          x.y = silu_f(bfhi(rv.x) + bfhi(cv.x) + rd[et]*w1c.y);
          x.z = silu_f(bflo(rv.y) + bflo(cv.y) + rd[et]*w1c.z);
          x.w = silu_f(bfhi(rv.y) + bfhi(cv.y) + rd[et]*w1c.w);
          uint2 p; p.x = pack2(x.x, x.y); p.y = pack2(x.z, x.w);
          *(uint2*)((char*)sptr(sb0, et*4 + ks2, lg2*16 + ecol) + 2*j0) = p;
        }
      }
    }
    __syncthreads();                                            // S1

    // GEMM2: ef = silu(t1 @ We2 + be2)
    f32x4 a2[2][4] = {};
#pragma unroll
    for (int et = 0; et < 4; ++et)
#pragma unroll
      for (int ks = 0; ks < 4; ++ks) {
        s16x8 b = *(const s16x8*)sptr(sb0, et*4+ks, lane);
        a2[0][et] = mfma16(wf2[0][ks], b, a2[0][et]);
        a2[1][et] = mfma16(wf2[1][ks], b, a2[1][et]);
      }
    // ep2: SiLU; frags into sb1; DPP segmented suffix-sum dedup -> agg_h atomics
#pragma unroll
    for (int et = 0; et < 4; ++et) {
      const int r_l = rr[et];
      f32x4 xx0, xx1;
#pragma unroll
      for (int f2 = 0; f2 < 2; ++f2) {
        const int f0 = (2*w+f2)*16 + (rgrp << 2);
        const int ks2 = f0 >> 5, lg2 = (f0 & 31) >> 3, j0 = f0 & 7;
        f32x4 b2 = *(const f32x4*)&s_vec[0][f0];
        f32x4 x = a2[f2][et];
        x.x = silu_f(x.x + b2.x); x.y = silu_f(x.y + b2.y);
        x.z = silu_f(x.z + b2.z); x.w = silu_f(x.w + b2.w);
        uint2 p; p.x = pack2(x.x, x.y); p.y = pack2(x.z, x.w);
        *(uint2*)((char*)sptr(sb1, et*4 + ks2, lg2*16 + ecol) + 2*j0) = p;
        if (f2 == 0) xx0 = x; else xx1 = x;
      }
#define SEG_ROUND(CTRL) { \
      int rn = dppi<CTRL>(r_l); \
      float m = (rn == r_l) ? 1.f : 0.f; \
      xx0.x += dppf<CTRL>(xx0.x)*m; \
      xx0.y += dppf<CTRL>(xx0.y)*m; \
      xx0.z += dppf<CTRL>(xx0.z)*m; \
      xx0.w += dppf<CTRL>(xx0.w)*m; \
      xx1.x += dppf<CTRL>(xx1.x)*m; \
      xx1.y += dppf<CTRL>(xx1.y)*m; \
      xx1.z += dppf<CTRL>(xx1.z)*m; \
      xx1.w += dppf<CTRL>(xx1.w)*m; }
      SEG_ROUND(0x101)
      SEG_ROUND(0x102)
      SEG_ROUND(0x104)
      SEG_ROUND(0x108)
#undef SEG_ROUND
      const int rprev = dppi<0x111>(r_l);
      if (rprev != r_l) {
        const int f0a = (2*w+0)*16 + (rgrp << 2);
        const int f0b = (2*w+1)*16 + (rgrp << 2);
        float* aga = aggh + (size_t)r_l*128 + f0a;
        float* agb = aggh + (size_t)r_l*128 + f0b;
        atomicAdd(aga+0, xx0.x); atomicAdd(aga+1, xx0.y);
        atomicAdd(aga+2, xx0.z); atomicAdd(aga+3, xx0.w);
        atomicAdd(agb+0, xx1.x); atomicAdd(agb+1, xx1.y);
        atomicAdd(agb+2, xx1.z); atomicAdd(agb+3, xx1.w);
      }
    }
    __syncthreads();                                            // S2

    // GEMM3: phi = silu(ef@Wc1+bc1) @ Wc2
    f32x4 a3[2][4] = {};
#pragma unroll
    for (int et = 0; et < 4; ++et)
#pragma unroll
      for (int ks = 0; ks < 4; ++ks) {
        s16x8 b = *(const s16x8*)sptr(sb1, et*4+ks, lane);
        a3[0][et] = mfma16(wf3[0][ks], b, a3[0][et]);
        a3[1][et] = mfma16(wf3[1][ks], b, a3[1][et]);
      }
#pragma unroll
    for (int et = 0; et < 4; ++et) {
      float p = 0.f;
#pragma unroll
      for (int f2 = 0; f2 < 2; ++f2) {
        const int f0 = (2*w+f2)*16 + (rgrp << 2);
        f32x4 bc = *(const f32x4*)&s_vec[1][f0];
        f32x4 wc = *(const f32x4*)&s_vec[3][f0];
        f32x4 x = a3[f2][et];
        p += silu_f(x.x + bc.x)*wc.x + silu_f(x.y + bc.y)*wc.y
           + silu_f(x.z + bc.z)*wc.z + silu_f(x.w + bc.w)*wc.w;
      }
      p += __shfl_xor(p, 16);
      p += __shfl_xor(p, 32);
      if (rgrp == 0) atomicAdd(&s_phi[et*16 + ecol], p);
    }
    __syncthreads();                                            // S3

    // coord aggregation (wave0): reload own lanes coalesced; segmented scan
    if (tid < 64) {
      int2 v = rc[e0 + tid];
      int r = v.x;
      f32x4 cd = *(const f32x4*)(cdr + 4*(size_t)(e0 + tid));
      float ph = s_phi[tid];
      float cx = cd.x*ph, cy = cd.y*ph, cz = cd.z*ph, c1 = 1.f;
#pragma unroll
      for (int d = 1; d < 64; d <<= 1) {
        const int sl = tid + d;
        int   r2 = __shfl(r,  sl, 64);
        float ux = __shfl(cx, sl, 64), uy = __shfl(cy, sl, 64);
        float uz = __shfl(cz, sl, 64), uw = __shfl(c1, sl, 64);
        if ((sl < 64) && (r2 == r)) { cx+=ux; cy+=uy; cz+=uz; c1+=uw; }
      }
      const int rp = __shfl(r, tid - 1, 64);
      if (tid == 0 || rp != r) {
        atomicAdd(&aggc[3*r+0], cx); atomicAdd(&aggc[3*r+1], cy);
        atomicAdd(&aggc[3*r+2], cz); atomicAdd(&cntb[r], c1);
      }
    }
    // no S4: sb0's next write is post-S3 for every wave; s_phi zero-write is
    // pre-S1(t+1) < post-S2(t+1) atomics; wave0 is sole s_phi[tid] reader.
  }
}

// ---------- merged: node model (blocks 0..781) || coord update (rest) -------
__global__ __launch_bounds__(256, 2)
void nodecoord_kernel(const unsigned short* __restrict__ A1, const float* __restrict__ h32,
                      const short* __restrict__ wp, const float* __restrict__ bn2,
                      const float* __restrict__ coord, const float* __restrict__ aggc,
                      const float* __restrict__ cntb, float* __restrict__ hout)
{
  if (blockIdx.x >= NODB) {           // coord part
    int i = (blockIdx.x - NODB)*256 + threadIdx.x;
    if (i < NN) {
      float inv = __builtin_amdgcn_rcpf(fmaxf(cntb[i], 1.f));
      hout[NHF + 3*i+0] = coord[3*i+0] + aggc[3*i+0]*inv;
      hout[NHF + 3*i+1] = coord[3*i+1] + aggc[3*i+1]*inv;
      hout[NHF + 3*i+2] = coord[3*i+2] + aggc[3*i+2]*inv;
    }
    return;
  }
  // node: h_out = h + silu(A1n + agg_h@Wn1b) @ Wn2 + bn2   (bn1 folded in A1)
  __shared__ short sA[16][64][8];
  __shared__ float s_vec[128];
  const int tid  = threadIdx.x, w = tid >> 6, lane = tid & 63;
  const int ecol = lane & 15, rgrp = lane >> 4;
  if (tid < 128) s_vec[tid] = bn2[tid];

  s16x8 wfa[2][4], wfb[2][4];          // Wn1b, Wn2
#pragma unroll
  for (int f2 = 0; f2 < 2; ++f2)
#pragma unroll
    for (int ks = 0; ks < 4; ++ks) {
      wfa[f2][ks] = *(const s16x8*)(wp + 5*16384 + ((((2*w+f2)<<2) + ks)*64 + lane)*8);
      wfb[f2][ks] = *(const s16x8*)(wp + 6*16384 + ((((2*w+f2)<<2) + ks)*64 + lane)*8);
    }

  const int n0 = blockIdx.x << 6;
  const int el = tid >> 2, q = tid & 3;
  const int fi0 = ((el >> 4) << 2) + q, er = el & 15;
  { // stage agg_h (lives in d_out h region) as bf16 frags
    const int node = n0 + el;
    if (node < NN) {
      const float* ap = hout + (size_t)node*128 + q*32;
#pragma unroll
      for (int lg = 0; lg < 4; ++lg) {
        f32x4 u = *(const f32x4*)(ap + lg*8);
        f32x4 v = *(const f32x4*)(ap + lg*8 + 4);
        uint4 o;
        o.x = pack2(u.x, u.y); o.y = pack2(u.z, u.w);
        o.z = pack2(v.x, v.y); o.w = pack2(v.z, v.w);
        *(uint4*)&sA[fi0][lg*16 + er][0] = o;
      }
    } else {
      s16x8 z = {};
#pragma unroll
      for (int lg = 0; lg < 4; ++lg) *(s16x8*)&sA[fi0][lg*16 + er][0] = z;
    }
  }
  __syncthreads();

  f32x4 acc[2][4] = {};
#pragma unroll
  for (int et = 0; et < 4; ++et)
#pragma unroll
    for (int ks = 0; ks < 4; ++ks) {
      s16x8 ba = *(const s16x8*)&sA[et*4+ks][lane][0];
      acc[0][et] = mfma16(wfa[0][ks], ba, acc[0][et]);
      acc[1][et] = mfma16(wfa[1][ks], ba, acc[1][et]);
    }
  __syncthreads();   // all reads of sA done; safe to overwrite with t frags

  // A1n gathers (gather-friendly layout: one uint4 per et covers both f2)
  uint4 g4[4];
  {
    const int gb = 256 + (w << 5) + (rgrp << 3);
#pragma unroll
    for (int et = 0; et < 4; ++et) {
      const int node = n0 + et*16 + ecol;
      if (node < NN) g4[et] = *(const uint4*)(A1 + (size_t)node*384 + gb);
      else { g4[et].x = 0u; g4[et].y = 0u; g4[et].z = 0u; g4[et].w = 0u; }
    }
  }
  // ep: t = silu(acc + A1n[node]) -> frags back into sA
#pragma unroll
  for (int f2 = 0; f2 < 2; ++f2) {
    const int ft = 2*w + f2, f0 = ft*16 + (rgrp << 2);
    const int ks2 = f0 >> 5, lg2 = (f0 & 31) >> 3, j0 = f0 & 7;
#pragma unroll
    for (int et = 0; et < 4; ++et) {
      uint2 g;
      g.x = f2 ? g4[et].z : g4[et].x;
      g.y = f2 ? g4[et].w : g4[et].y;
      f32x4 x = acc[f2][et];
      x.x = silu_f(x.x + bflo(g.x));
      x.y = silu_f(x.y + bfhi(g.x));
      x.z = silu_f(x.z + bflo(g.y));
      x.w = silu_f(x.w + bfhi(g.y));
      uint2 p; p.x = pack2(x.x, x.y); p.y = pack2(x.z, x.w);
      *(uint2*)&sA[et*4 + ks2][lg2*16 + ecol][j0] = p;
    }
  }
  __syncthreads();

  f32x4 a2[2][4] = {};
#pragma unroll
  for (int et = 0; et < 4; ++et)
#pragma unroll
    for (int ks = 0; ks < 4; ++ks) {
      s16x8 b = *(const s16x8*)&sA[et*4+ks][lane][0];
      a2[0][et] = mfma16(wfb[0][ks], b, a2[0][et]);
      a2[1][et] = mfma16(wfb[1][ks], b, a2[1][et]);
    }
  // h_out = h + a2 + bn2, written directly (16B per lane)
#pragma unroll
  for (int f2 = 0; f2 < 2; ++f2) {
    const int f0 = (2*w+f2)*16 + (rgrp << 2);
    f32x4 b2 = *(const f32x4*)&s_vec[f0];
#pragma unroll
    for (int et = 0; et < 4; ++et) {
      const int node = n0 + et*16 + ecol;
      if (node < NN) {
        f32x4 hv = *(const f32x4*)(h32 + (size_t)node*128 + f0);
        f32x4 x = a2[f2][et];
        x.x += b2.x + hv.x; x.y += b2.y + hv.y;
        x.z += b2.z + hv.z; x.w += b2.w + hv.w;
        *(f32x4*)(hout + (size_t)node*128 + f0) = x;
      }
    }
  }
}

extern "C" void kernel_launch(void* const* d_in, const int* in_sizes, int n_in,
                              void* d_out, int out_size, void* d_ws, size_t ws_size,
                              hipStream_t stream)
{
  (void)in_sizes; (void)n_in; (void)out_size; (void)ws_size;
  const float* h    = (const float*)d_in[0];
  const float* crd  = (const float*)d_in[1];
  const int*   eidx = (const int*)  d_in[2];
  const float* We1  = (const float*)d_in[3];
  const float* be1  = (const float*)d_in[4];
  const float* We2  = (const float*)d_in[5];
  const float* be2  = (const float*)d_in[6];
  const float* Wn1  = (const float*)d_in[7];
  const float* bn1  = (const float*)d_in[8];
  const float* Wn2  = (const float*)d_in[9];
  const float* bn2  = (const float*)d_in[10];
  const float* Wc1  = (const float*)d_in[11];
  const float* bc1  = (const float*)d_in[12];
  const float* Wc2  = (const float*)d_in[13];
  float* out = (float*)d_out;
  char*  ws  = (char*)d_ws;

  short*          wp   = (short*)ws;                       //    229,376 B
  unsigned short* A1   = (unsigned short*)(ws + 229376);   // 38,400,000 B
  float*          aggc = (float*)(ws + 38629376);          //    600,000 B
  float*          cntb = (float*)(ws + 39229376);          //    200,000 B
  int*            hist = (int*)  (ws + 39429376);          //    200,000 B
  int*            cur  = (int*)  (ws + 39629376);          //    200,000 B
  int*            btot = (int*)  (ws + 39829376);          //      1,024 B
  int2*           rc   = (int2*) (ws + 39830400);          // 12,800,000 B
  float*          cdr  = (float*)(ws + 52630400);          // 25,600,000 B (end 78,230,400)

  // zero accumulators every call (harness does not re-poison between replays)
  hipMemsetAsync(out, 0, (size_t)NHF*4, stream);           // agg_h region of d_out
  hipMemsetAsync(ws + 38629376, 0, 800000, stream);        // agg_c + cnt
  hipMemsetAsync(ws + 39429376, 0, 200000, stream);        // hist

  pack_weights<<<dim3(224), dim3(64), 0, stream>>>(We1, We2, Wc1, Wn1, Wn2, wp);
  a1hist_kernel<<<dim3(A1B + 6250), dim3(256), 0, stream>>>(h, wp, be1, bn1, A1, eidx, hist);
  scanA<<<dim3(196), dim3(256), 0, stream>>>(hist, cur, btot);
  scanB<<<dim3(1), dim3(256), 0, stream>>>(btot);
  scatter_k<<<dim3(6250), dim3(256), 0, stream>>>(eidx, cur, btot, crd, rc, cdr);
  edge_kernel<<<dim3(1924), dim3(256), 0, stream>>>(A1, cdr, rc, wp,
                                                    be2, bc1, We1, Wc2,
                                                    out, aggc, cntb);
  nodecoord_kernel<<<dim3(NODB + 196), dim3(256), 0, stream>>>(A1, h, wp, bn2,
                                                               crd, aggc, cntb, out);
}